// Round 1
// baseline (7389.981 us; speedup 1.0000x reference)
//
#include <hip/hip_runtime.h>
#include <hip/hip_bf16.h>

#define CDIM 256
#define EPS 1e-5f
#define SLOPE 0.01f

// ---------------- workspace layout (float offsets) ----------------
enum : size_t {
  OFF_WS_HF   = 0,          // [4,256,3,3] = 9216
  OFF_WS_LF   = 9216,
  OFF_POOL_HF = 18432,      // [4,256]
  OFF_POOL_LF = 19456,
  OFF_WP_HF   = 20480,
  OFF_BS_HF   = 21504,
  OFF_WP_LF   = 22528,
  OFF_BS_LF   = 23552,
  OFF_MEAN_HF = 24576,
  OFF_RSTD_HF = 25600,
  OFF_MEAN_LF = 26624,
  OFF_RSTD_LF = 27648,
  OFF_BUFY    = 32768,                    // 4*256*128*128 = 16777216 (y_hf, later y_lf, later avgpool)
  OFF_BUFHF   = OFF_BUFY + 16777216,      // hf after ada_conv+lrelu
  OFF_BUFLF   = OFF_BUFHF + 16777216,     // lf after ada_conv+lrelu (4*256*64*64)
  TOTAL_F     = OFF_BUFLF + 4194304,
};

// fallback scratch in case ws_size is too small (BSS, allocated at module load)
__device__ float g_scratch[TOTAL_F];

__device__ __forceinline__ int refl(int q, int n) {
  // reflect for pad==1: -1 -> 1, n -> n-2, else identity
  return q < 0 ? -q : (q >= n ? 2 * n - 2 - q : q);
}

__device__ __forceinline__ float lrelu(float v) {
  return v >= 0.f ? v : SLOPE * v;
}

// ---------------- kernel_predict: spatial weights ws = conv(rpad(s,1), sw) + sb ----------------
// grid = B*C blocks (one per (b, oc)), block = 256 (one thread per input channel)
__global__ __launch_bounds__(256) void k_ws(const float* __restrict__ s,
                                            const float* __restrict__ sw,
                                            const float* __restrict__ sb,
                                            float* __restrict__ ws_out) {
  int bo = blockIdx.x;           // b*C + o
  int o  = bo & (CDIM - 1);
  int c  = threadIdx.x;
  int b  = bo >> 8;

  float sv[9], wv[9];
  const float* sp = s  + (size_t)(b * CDIM + c) * 9;
  const float* wp = sw + (size_t)(o * CDIM + c) * 9;
#pragma unroll
  for (int i = 0; i < 9; i++) { sv[i] = sp[i]; wv[i] = wp[i]; }

  float out9[9];
#pragma unroll
  for (int i = 0; i < 3; i++) {
#pragma unroll
    for (int j = 0; j < 3; j++) {
      float a = 0.f;
#pragma unroll
      for (int dy = 0; dy < 3; dy++) {
        int u = i + dy - 1; u = (u < 0) ? 1 : (u > 2 ? 1 : u);   // reflect in size 3
#pragma unroll
        for (int dx = 0; dx < 3; dx++) {
          int v = j + dx - 1; v = (v < 0) ? 1 : (v > 2 ? 1 : v);
          a += sv[u * 3 + v] * wv[dy * 3 + dx];
        }
      }
      out9[i * 3 + j] = a;
    }
  }

  __shared__ float red[256 * 9];
#pragma unroll
  for (int i = 0; i < 9; i++) red[c * 9 + i] = out9[i];
  __syncthreads();
  for (int st = 128; st > 0; st >>= 1) {
    if (c < st) {
#pragma unroll
      for (int i = 0; i < 9; i++) red[c * 9 + i] += red[(c + st) * 9 + i];
    }
    __syncthreads();
  }
  if (c < 9) ws_out[(size_t)bo * 9 + c] = red[c] + sb[o];
}

// ---------------- pooled = s.mean(axis=(2,3)) ----------------
__global__ void k_pool(const float* __restrict__ s, float* __restrict__ pooled, int n) {
  int i = blockIdx.x * 256 + threadIdx.x;
  if (i >= n) return;
  const float* p = s + (size_t)i * 9;
  float a = 0.f;
#pragma unroll
  for (int j = 0; j < 9; j++) a += p[j];
  pooled[i] = a * (1.f / 9.f);
}

// ---------------- w_point / bias = pooled @ {pw,bw}^T + {pb,bb} ----------------
// grid = B, block = 256 (one thread per output channel)
__global__ __launch_bounds__(256) void k_point(const float* __restrict__ pooled,
                                               const float* __restrict__ pw,
                                               const float* __restrict__ pb,
                                               const float* __restrict__ bw,
                                               const float* __restrict__ bb,
                                               float* __restrict__ wp_out,
                                               float* __restrict__ bs_out) {
  int b = blockIdx.x, o = threadIdx.x;
  __shared__ float pl[CDIM];
  pl[o] = pooled[b * CDIM + o];
  __syncthreads();
  float a = pb[o], d = bb[o];
  for (int c = 0; c < CDIM; c++) {
    float p = pl[c];
    a += p * pw[o * CDIM + c];
    d += p * bw[o * CDIM + c];
  }
  wp_out[b * CDIM + o] = a;
  bs_out[b * CDIM + o] = d;
}

// ---------------- instance norm stats per (b,c) plane ----------------
__global__ __launch_bounds__(256) void k_istats(const float* __restrict__ x,
                                                float* __restrict__ mean,
                                                float* __restrict__ rstd, int HW) {
  int plane = blockIdx.x;
  const float4* p = (const float4*)(x + (size_t)plane * HW);
  int n4 = HW >> 2;
  float s = 0.f, q = 0.f;
  for (int i = threadIdx.x; i < n4; i += 256) {
    float4 v = p[i];
    s += v.x + v.y + v.z + v.w;
    q += v.x * v.x + v.y * v.y + v.z * v.z + v.w * v.w;
  }
  __shared__ float rs[256], rq[256];
  rs[threadIdx.x] = s; rq[threadIdx.x] = q;
  __syncthreads();
  for (int st = 128; st > 0; st >>= 1) {
    if (threadIdx.x < st) {
      rs[threadIdx.x] += rs[threadIdx.x + st];
      rq[threadIdx.x] += rq[threadIdx.x + st];
    }
    __syncthreads();
  }
  if (threadIdx.x == 0) {
    float m = rs[0] / HW;
    float v = rq[0] / HW - m * m;
    mean[plane] = m;
    rstd[plane] = rsqrtf(v + EPS);
  }
}

// ---------------- fused instance-norm + dynamic depthwise + pointwise scale/bias ----------------
// y[b,c,h,w] = wp[b,c] * sum_{dy,dx} ws[b,c,dy,dx]*( (x[refl]-m)*r ) + bs[b,c]
__global__ __launch_bounds__(256) void k_dwpw(const float* __restrict__ x,
                                              const float* __restrict__ ws,
                                              const float* __restrict__ mean,
                                              const float* __restrict__ rstd,
                                              const float* __restrict__ wp,
                                              const float* __restrict__ bs,
                                              float* __restrict__ y, int H, int W) {
  int HW = H * W;
  int blocksPerPlane = HW >> 8;
  int plane = blockIdx.x / blocksPerPlane;
  int px = (blockIdx.x % blocksPerPlane) * 256 + threadIdx.x;
  int yy = px / W, xx = px - yy * W;
  float m = mean[plane], r = rstd[plane], sc = wp[plane], bi = bs[plane];
  const float* wsp = ws + (size_t)plane * 9;
  float w9[9];
#pragma unroll
  for (int i = 0; i < 9; i++) w9[i] = wsp[i];
  const float* xp = x + (size_t)plane * HW;
  float a = 0.f;
#pragma unroll
  for (int dy = 0; dy < 3; dy++) {
    int sy = refl(yy + dy - 1, H);
#pragma unroll
    for (int dx = 0; dx < 3; dx++) {
      int sx = refl(xx + dx - 1, W);
      a += w9[dy * 3 + dx] * (xp[sy * W + sx] - m);
    }
  }
  a *= r;
  y[(size_t)plane * HW + px] = a * sc + bi;
}

// ---------------- 3x3 reflect-pad conv, C->C ----------------
// tile: 16 oc x (8 rows x 32 cols). block 256. grid (W/32, H/8, B*16).
// UP: input is half-res, nearest-upsample on read. ACCUM: out += conv. RELU: leaky-relu at end.
template <bool UPS, bool ACCUM, bool RELU>
__global__ __launch_bounds__(256) void k_conv3x3(const float* __restrict__ in,
                                                 const float* __restrict__ wt,
                                                 const float* __restrict__ bias,
                                                 float* __restrict__ out,
                                                 int H, int W, int inH, int inW) {
  int x0 = blockIdx.x * 32, y0 = blockIdx.y * 8;
  int b = blockIdx.z >> 4, og = blockIdx.z & 15;
  int t = threadIdx.x;
  int ocg = t >> 6;          // 0..3
  int pix = t & 63;
  int lx = (pix & 7) * 4, ly = pix >> 3;
  int ocbase = og * 16 + ocg * 4;

  __shared__ float tile[10 * 35];
  float acc[4][4] = {};

  const size_t inPlane = (size_t)inH * inW;
  const float* inb = in + (size_t)b * CDIM * inPlane;

  for (int ic = 0; ic < CDIM; ic++) {
    __syncthreads();
    const float* src = inb + ic * inPlane;
    for (int i = t; i < 340; i += 256) {
      int gr = i / 34, gc = i - gr * 34;
      int qq = refl(y0 - 1 + gr, H);
      int pp = refl(x0 - 1 + gc, W);
      int sy, sx;
      if (UPS) { sy = qq >> 1; sx = pp >> 1; } else { sy = qq; sx = pp; }
      tile[gr * 35 + gc] = src[sy * inW + sx];
    }
    __syncthreads();

    const float* wtb = wt + ((size_t)ocbase * CDIM + ic) * 9;
#pragma unroll
    for (int r = 0; r < 3; r++) {
      float v[6];
#pragma unroll
      for (int cc = 0; cc < 6; cc++) v[cc] = tile[(ly + r) * 35 + lx + cc];
#pragma unroll
      for (int oo = 0; oo < 4; oo++) {
        const float* w3 = wtb + (size_t)oo * CDIM * 9 + r * 3;
        float w0 = w3[0], w1 = w3[1], w2 = w3[2];
#pragma unroll
        for (int p = 0; p < 4; p++)
          acc[oo][p] += w0 * v[p] + w1 * v[p + 1] + w2 * v[p + 2];
      }
    }
  }

#pragma unroll
  for (int oo = 0; oo < 4; oo++) {
    int oc = ocbase + oo;
    float bv = bias ? bias[oc] : 0.f;
    size_t o0 = ((size_t)(b * CDIM + oc) * H + (y0 + ly)) * W + x0 + lx;
    float4 r;
    r.x = acc[oo][0] + bv;
    r.y = acc[oo][1] + bv;
    r.z = acc[oo][2] + bv;
    r.w = acc[oo][3] + bv;
    if (ACCUM) {
      float4 e = *(const float4*)(out + o0);
      r.x += e.x; r.y += e.y; r.z += e.z; r.w += e.w;
    }
    if (RELU) {
      r.x = lrelu(r.x); r.y = lrelu(r.y); r.z = lrelu(r.z); r.w = lrelu(r.w);
    }
    *(float4*)(out + o0) = r;
  }
}

// ---------------- 2x2 average pool ----------------
__global__ void k_avgpool(const float* __restrict__ x, float* __restrict__ y, int H, int W) {
  int oH = H >> 1, oW = W >> 1, oHW = oH * oW;
  int i = blockIdx.x * 256 + threadIdx.x;
  int plane = i / oHW;
  int r = i - plane * oHW;
  int Y = r / oW, X = r - Y * oW;
  const float* p = x + (size_t)plane * H * W;
  float a = p[(2 * Y) * W + 2 * X] + p[(2 * Y) * W + 2 * X + 1] +
            p[(2 * Y + 1) * W + 2 * X] + p[(2 * Y + 1) * W + 2 * X + 1];
  y[(size_t)plane * oHW + r] = 0.25f * a;
}

// ---------------- host ----------------
extern "C" void kernel_launch(void* const* d_in, const int* in_sizes, int n_in,
                              void* d_out, int out_size, void* d_ws, size_t ws_size,
                              hipStream_t stream) {
  (void)in_sizes; (void)n_in; (void)out_size;
  const float* c_hf = (const float*)d_in[0];
  const float* c_lf = (const float*)d_in[1];
  const float* s_hf = (const float*)d_in[2];
  const float* s_lf = (const float*)d_in[3];
  const float* h_sw = (const float*)d_in[4];
  const float* h_sb = (const float*)d_in[5];
  const float* h_pw = (const float*)d_in[6];
  const float* h_pb = (const float*)d_in[7];
  const float* h_bw = (const float*)d_in[8];
  const float* h_bb = (const float*)d_in[9];
  const float* l_sw = (const float*)d_in[10];
  const float* l_sb = (const float*)d_in[11];
  const float* l_pw = (const float*)d_in[12];
  const float* l_pb = (const float*)d_in[13];
  const float* l_bw = (const float*)d_in[14];
  const float* l_bb = (const float*)d_in[15];
  const float* ada_h_w = (const float*)d_in[16];
  const float* ada_h_b = (const float*)d_in[17];
  const float* ada_l_w = (const float*)d_in[18];
  const float* ada_l_b = (const float*)d_in[19];
  const float* h2h = (const float*)d_in[20];
  const float* l2h = (const float*)d_in[21];
  const float* h2l = (const float*)d_in[22];
  const float* l2l = (const float*)d_in[23];

  const int B = 4, H = 128, W = 128;

  float* base;
  size_t need = (size_t)TOTAL_F * sizeof(float);
  if (ws_size >= need) {
    base = (float*)d_ws;
  } else {
    void* p = nullptr;
    hipGetSymbolAddress(&p, HIP_SYMBOL(g_scratch));
    base = (float*)p;
  }

  float* ws_hf   = base + OFF_WS_HF;
  float* ws_lf   = base + OFF_WS_LF;
  float* pool_hf = base + OFF_POOL_HF;
  float* pool_lf = base + OFF_POOL_LF;
  float* wp_hf   = base + OFF_WP_HF;
  float* bs_hf   = base + OFF_BS_HF;
  float* wp_lf   = base + OFF_WP_LF;
  float* bs_lf   = base + OFF_BS_LF;
  float* mean_hf = base + OFF_MEAN_HF;
  float* rstd_hf = base + OFF_RSTD_HF;
  float* mean_lf = base + OFF_MEAN_LF;
  float* rstd_lf = base + OFF_RSTD_LF;
  float* bufY    = base + OFF_BUFY;    // 64 MB scratch (y_hf -> y_lf -> avgpool)
  float* bufHF   = base + OFF_BUFHF;
  float* bufLF   = base + OFF_BUFLF;

  float* out_hf = (float*)d_out;                 // [4,256,128,128]
  float* out_lf = (float*)d_out + 16777216;      // [4,256,64,64]

  // --- kernel_predict (hf & lf) ---
  k_ws<<<dim3(B * CDIM), dim3(256), 0, stream>>>(s_hf, h_sw, h_sb, ws_hf);
  k_ws<<<dim3(B * CDIM), dim3(256), 0, stream>>>(s_lf, l_sw, l_sb, ws_lf);
  k_pool<<<dim3(4), dim3(256), 0, stream>>>(s_hf, pool_hf, B * CDIM);
  k_pool<<<dim3(4), dim3(256), 0, stream>>>(s_lf, pool_lf, B * CDIM);
  k_point<<<dim3(B), dim3(256), 0, stream>>>(pool_hf, h_pw, h_pb, h_bw, h_bb, wp_hf, bs_hf);
  k_point<<<dim3(B), dim3(256), 0, stream>>>(pool_lf, l_pw, l_pb, l_bw, l_bb, wp_lf, bs_lf);

  // --- instance norm stats ---
  k_istats<<<dim3(B * CDIM), dim3(256), 0, stream>>>(c_hf, mean_hf, rstd_hf, H * W);
  k_istats<<<dim3(B * CDIM), dim3(256), 0, stream>>>(c_lf, mean_lf, rstd_lf, (H / 2) * (W / 2));

  // --- hf branch: depthwise+pointwise then shared conv (+lrelu) ---
  k_dwpw<<<dim3(B * CDIM * (H * W / 256)), dim3(256), 0, stream>>>(
      c_hf, ws_hf, mean_hf, rstd_hf, wp_hf, bs_hf, bufY, H, W);
  k_conv3x3<false, false, true><<<dim3(W / 32, H / 8, B * 16), dim3(256), 0, stream>>>(
      bufY, ada_h_w, ada_h_b, bufHF, H, W, H, W);

  // --- lf branch ---
  k_dwpw<<<dim3(B * CDIM * (H * W / 4 / 256)), dim3(256), 0, stream>>>(
      c_lf, ws_lf, mean_lf, rstd_lf, wp_lf, bs_lf, bufY, H / 2, W / 2);
  k_conv3x3<false, false, true><<<dim3(W / 64, H / 16, B * 16), dim3(256), 0, stream>>>(
      bufY, ada_l_w, ada_l_b, bufLF, H / 2, W / 2, H / 2, W / 2);

  // --- lf_out = lrelu(conv(lf,l2l) + conv(avgpool2(hf),h2l)) ---
  k_avgpool<<<dim3(B * CDIM * (H / 2) * (W / 2) / 256), dim3(256), 0, stream>>>(bufHF, bufY, H, W);
  k_conv3x3<false, false, false><<<dim3(W / 64, H / 16, B * 16), dim3(256), 0, stream>>>(
      bufLF, l2l, nullptr, out_lf, H / 2, W / 2, H / 2, W / 2);
  k_conv3x3<false, true, true><<<dim3(W / 64, H / 16, B * 16), dim3(256), 0, stream>>>(
      bufY, h2l, nullptr, out_lf, H / 2, W / 2, H / 2, W / 2);

  // --- hf_out = lrelu(conv(hf,h2h) + conv(upsample2(lf),l2h)) ---
  k_conv3x3<false, false, false><<<dim3(W / 32, H / 8, B * 16), dim3(256), 0, stream>>>(
      bufHF, h2h, nullptr, out_hf, H, W, H, W);
  k_conv3x3<true, true, true><<<dim3(W / 32, H / 8, B * 16), dim3(256), 0, stream>>>(
      bufLF, l2h, nullptr, out_hf, H, W, H / 2, W / 2);
}

// Round 2
// 638.370 us; speedup vs baseline: 11.5763x; 11.5763x over previous
//
#include <hip/hip_runtime.h>
#include <hip/hip_bf16.h>

#define CDIM 256
#define EPS 1e-5f
#define SLOPE 0.01f

using f32x4  = __attribute__((ext_vector_type(4))) float;
typedef __bf16 bf16x8 __attribute__((ext_vector_type(8)));

// ---------------- workspace layout ----------------
enum : size_t {
  OFF_WS_HF   = 0,
  OFF_WS_LF   = 9216,
  OFF_POOL_HF = 18432,
  OFF_POOL_LF = 19456,
  OFF_WP_HF   = 20480,
  OFF_BS_HF   = 21504,
  OFF_WP_LF   = 22528,
  OFF_BS_LF   = 23552,
  OFF_MEAN_HF = 24576,
  OFF_RSTD_HF = 25600,
  OFF_MEAN_LF = 26624,
  OFF_RSTD_LF = 27648,
  OFF_U16     = 32768,          // start of ushort region (float units)
};
// ushort offsets relative to u16 base
enum : size_t {
  U_YH  = 0,          // [4][128][128][256] bf16
  U_YL  = 16777216,   // [4][64][64][256]
  U_HFA = 20971520,   // [4][128][128][256]
  U_LFA = 37748736,   // [4][64][64][256]
  U_HFP = 41943040,   // [4][64][64][256]
  U_PK  = 46137344,   // 6 packed weights, each 589824
  PK_SZ = 589824,
  U_END = U_PK + 6 * PK_SZ,
};
enum : size_t { TOTAL_F = OFF_U16 + (U_END + 1) / 2 };

__device__ float g_scratch[TOTAL_F];

__device__ __forceinline__ int refl(int q, int n) {
  return q < 0 ? -q : (q >= n ? 2 * n - 2 - q : q);
}
__device__ __forceinline__ float lrelu(float v) { return v >= 0.f ? v : SLOPE * v; }
__device__ __forceinline__ unsigned short f2bf(float f) {
  unsigned int u = __float_as_uint(f);
  u += 0x7fffu + ((u >> 16) & 1u);
  return (unsigned short)(u >> 16);
}
__device__ __forceinline__ float bf2f(unsigned short h) {
  return __uint_as_float(((unsigned int)h) << 16);
}
__device__ __forceinline__ void gload_lds16(const void* g, void* l) {
  __builtin_amdgcn_global_load_lds(
      (const __attribute__((address_space(1))) unsigned int*)g,
      (__attribute__((address_space(3))) unsigned int*)l, 16, 0, 0);
}

// ---------------- kernel_predict: spatial weights ----------------
__global__ __launch_bounds__(256) void k_ws(const float* __restrict__ s,
                                            const float* __restrict__ sw,
                                            const float* __restrict__ sb,
                                            float* __restrict__ ws_out) {
  int bo = blockIdx.x;
  int o = bo & (CDIM - 1);
  int c = threadIdx.x;
  int b = bo >> 8;
  float sv[9], wv[9];
  const float* sp = s + (size_t)(b * CDIM + c) * 9;
  const float* wp = sw + (size_t)(o * CDIM + c) * 9;
#pragma unroll
  for (int i = 0; i < 9; i++) { sv[i] = sp[i]; wv[i] = wp[i]; }
  float out9[9];
#pragma unroll
  for (int i = 0; i < 3; i++)
#pragma unroll
    for (int j = 0; j < 3; j++) {
      float a = 0.f;
#pragma unroll
      for (int dy = 0; dy < 3; dy++) {
        int u = i + dy - 1; u = (u < 0) ? 1 : (u > 2 ? 1 : u);
#pragma unroll
        for (int dx = 0; dx < 3; dx++) {
          int v = j + dx - 1; v = (v < 0) ? 1 : (v > 2 ? 1 : v);
          a += sv[u * 3 + v] * wv[dy * 3 + dx];
        }
      }
      out9[i * 3 + j] = a;
    }
  __shared__ float red[256 * 9];
#pragma unroll
  for (int i = 0; i < 9; i++) red[c * 9 + i] = out9[i];
  __syncthreads();
  for (int st = 128; st > 0; st >>= 1) {
    if (c < st)
#pragma unroll
      for (int i = 0; i < 9; i++) red[c * 9 + i] += red[(c + st) * 9 + i];
    __syncthreads();
  }
  if (c < 9) ws_out[(size_t)bo * 9 + c] = red[c] + sb[o];
}

__global__ void k_pool(const float* __restrict__ s, float* __restrict__ pooled, int n) {
  int i = blockIdx.x * 256 + threadIdx.x;
  if (i >= n) return;
  const float* p = s + (size_t)i * 9;
  float a = 0.f;
#pragma unroll
  for (int j = 0; j < 9; j++) a += p[j];
  pooled[i] = a * (1.f / 9.f);
}

__global__ __launch_bounds__(256) void k_point(const float* __restrict__ pooled,
                                               const float* __restrict__ pw,
                                               const float* __restrict__ pb,
                                               const float* __restrict__ bw,
                                               const float* __restrict__ bb,
                                               float* __restrict__ wp_out,
                                               float* __restrict__ bs_out) {
  int b = blockIdx.x, o = threadIdx.x;
  __shared__ float pl[CDIM];
  pl[o] = pooled[b * CDIM + o];
  __syncthreads();
  float a = pb[o], d = bb[o];
  for (int c = 0; c < CDIM; c++) {
    float p = pl[c];
    a += p * pw[o * CDIM + c];
    d += p * bw[o * CDIM + c];
  }
  wp_out[b * CDIM + o] = a;
  bs_out[b * CDIM + o] = d;
}

__global__ __launch_bounds__(256) void k_istats(const float* __restrict__ x,
                                                float* __restrict__ mean,
                                                float* __restrict__ rstd, int HW) {
  int plane = blockIdx.x;
  const float4* p = (const float4*)(x + (size_t)plane * HW);
  int n4 = HW >> 2;
  float s = 0.f, q = 0.f;
  for (int i = threadIdx.x; i < n4; i += 256) {
    float4 v = p[i];
    s += v.x + v.y + v.z + v.w;
    q += v.x * v.x + v.y * v.y + v.z * v.z + v.w * v.w;
  }
  __shared__ float rs[256], rq[256];
  rs[threadIdx.x] = s; rq[threadIdx.x] = q;
  __syncthreads();
  for (int st = 128; st > 0; st >>= 1) {
    if (threadIdx.x < st) {
      rs[threadIdx.x] += rs[threadIdx.x + st];
      rq[threadIdx.x] += rq[threadIdx.x + st];
    }
    __syncthreads();
  }
  if (threadIdx.x == 0) {
    float m = rs[0] / HW;
    float v = rq[0] / HW - m * m;
    mean[plane] = m;
    rstd[plane] = rsqrtf(v + EPS);
  }
}

// ---------------- weight pack: OIHW f32 -> [tap][icc][mf][lane][8] bf16 ----------------
__global__ void k_packw(const float* __restrict__ w, unsigned short* __restrict__ pk) {
  int i = blockIdx.x * 256 + threadIdx.x;   // < 589824
  int j = i & 7, l = (i >> 3) & 63, mf = (i >> 9) & 15, icc = (i >> 13) & 7, tap = i >> 16;
  int oc = mf * 16 + (l & 15);
  int ic = icc * 32 + (l >> 4) * 8 + j;
  pk[i] = f2bf(w[((size_t)oc * 256 + ic) * 9 + tap]);
}

// ---------------- fused IN + dynamic depthwise + pointwise -> NHWC bf16 ----------------
// grid((W/64)*4, H, B), block 256. tile: 64 ic x 64 x of one (b,y) row.
template <int LW>
__global__ __launch_bounds__(256) void k_dwt(const float* __restrict__ x,
                                             const float* __restrict__ ws,
                                             const float* __restrict__ mean,
                                             const float* __restrict__ rstd,
                                             const float* __restrict__ wp,
                                             const float* __restrict__ bs,
                                             unsigned short* __restrict__ out) {
  constexpr int W = 1 << LW, H = W, HW = W * W;
  int t = threadIdx.x;
  int xt = (LW > 6) ? (blockIdx.x & ((W >> 6) - 1)) : 0;
  int icb = (LW > 6) ? (blockIdx.x >> (LW - 6)) : blockIdx.x;
  int y = blockIdx.y, b = blockIdx.z;
  __shared__ unsigned short tr[64][66];
  int xl = t & 63;
  int xx = xt * 64 + xl;
  int sy0 = refl(y - 1, H), sy1 = y, sy2 = refl(y + 1, H);
  int sx0 = refl(xx - 1, W), sx2 = refl(xx + 1, W);
#pragma unroll
  for (int rr = 0; rr < 16; ++rr) {
    int icl = rr * 4 + (t >> 6);
    int plane = b * CDIM + icb * 64 + icl;
    const float* xp = x + (size_t)plane * HW;
    float m = mean[plane], r = rstd[plane], sc = wp[plane], bi = bs[plane];
    const float* w9 = ws + (size_t)plane * 9;
    float a = w9[0] * (xp[sy0 * W + sx0] - m) + w9[1] * (xp[sy0 * W + xx] - m) +
              w9[2] * (xp[sy0 * W + sx2] - m) + w9[3] * (xp[sy1 * W + sx0] - m) +
              w9[4] * (xp[sy1 * W + xx] - m) + w9[5] * (xp[sy1 * W + sx2] - m) +
              w9[6] * (xp[sy2 * W + sx0] - m) + w9[7] * (xp[sy2 * W + xx] - m) +
              w9[8] * (xp[sy2 * W + sx2] - m);
    tr[icl][xl] = f2bf(a * r * sc + bi);
  }
  __syncthreads();
#pragma unroll
  for (int rr = 0; rr < 16; ++rr) {
    int xl2 = rr * 4 + (t >> 6);
    int icl2 = t & 63;
    out[((size_t)((b * H + y) * W + xt * 64 + xl2)) * CDIM + icb * 64 + icl2] = tr[icl2][xl2];
  }
}

// ---------------- 2x2 avg pool on NHWC bf16 ----------------
__global__ __launch_bounds__(256) void k_pool_nhwc(const unsigned short* __restrict__ in,
                                                   unsigned short* __restrict__ out) {
  int t = threadIdx.x;
  int p = blockIdx.x;                 // (b*64+Y)*64+X
  int X = p & 63, Y = (p >> 6) & 63, b = p >> 12;
  const unsigned short* s = in + (((size_t)(b * 128 + 2 * Y) * 128 + 2 * X) * CDIM + t);
  float a = bf2f(s[0]) + bf2f(s[CDIM]) + bf2f(s[128 * CDIM]) + bf2f(s[128 * CDIM + CDIM]);
  out[(size_t)p * CDIM + t] = f2bf(0.25f * a);
}

// ---------------- MFMA implicit-GEMM 3x3 reflect conv ----------------
// block 256 (4 waves), tile 64 oc x 256 pixels; K-step = tap x 32 ic.
// grid(npix/256, 4). DUAL: sum of two convs (srcB may be nearest-upsampled).
template <int LW, bool DUAL, bool UPSB, bool NCHWOUT>
__global__ __launch_bounds__(256) void k_conv_mfma(
    const unsigned short* __restrict__ srcA, const unsigned short* __restrict__ srcB,
    const unsigned short* __restrict__ wpkA, const unsigned short* __restrict__ wpkB,
    const float* __restrict__ bias, void* __restrict__ outp) {
  constexpr int W = 1 << LW, H = W, HW = W * W;
  constexpr int ROWS = 256 >> LW;       // rows of pixels per block
  constexpr int R = ROWS + 2, Cw = W + 2;
  constexpr int RC = R * Cw;
  constexpr int RCPAD = (RC + 63) & ~63;
  __shared__ __align__(16) unsigned short tin[RCPAD * 32];
  __shared__ __align__(16) unsigned short wlds[4 * 64 * 8];

  const int t = threadIdx.x;
  const int l = t & 63, wv = t >> 6;
  const int l15 = l & 15, l4 = l >> 4;
  const int pixbase = blockIdx.x * 256;
  const int mb = blockIdx.y;
  const int b = pixbase >> (2 * LW);
  const int y0 = (pixbase >> LW) & (H - 1);

  f32x4 acc[4][4];
#pragma unroll
  for (int mi = 0; mi < 4; mi++)
#pragma unroll
    for (int nf = 0; nf < 4; nf++) acc[mi][nf] = (f32x4){0.f, 0.f, 0.f, 0.f};

  const int nsrc = DUAL ? 2 : 1;
  for (int src = 0; src < nsrc; ++src) {
    const unsigned short* ysrc = src ? srcB : srcA;
    const unsigned short* wpk = src ? wpkB : wpkA;
    const bool ups = UPSB && (src == 1);
    for (int icc = 0; icc < 8; ++icc) {
      for (int tap = 0; tap < 9; ++tap) {
        __syncthreads();
        if (tap == 0) {
          // stage input tile [R][Cw][32ic] with ic-slot XOR-swizzled by (col&3)
#pragma unroll
          for (int it = 0; it < RCPAD / 64; ++it) {
            int rc = it * 64 + (t >> 2);
            int rcc = rc < RC - 1 ? rc : RC - 1;
            int r = rcc / Cw, tc = rcc - r * Cw;
            int gy = refl(y0 - 1 + r, H);
            int gx = refl(tc - 1, W);
            int sy, sx, sw;
            if (ups) { sy = gy >> 1; sx = gx >> 1; sw = W >> 1; }
            else     { sy = gy;      sx = gx;      sw = W; }
            int gsrc = (t & 3) ^ (tc & 3);
            const unsigned short* sp =
                ysrc + (((size_t)(b * sw + sy) * sw + sx) * CDIM + icc * 32 + gsrc * 8);
            gload_lds16(sp, &tin[(size_t)(it * 256 + t) * 8]);
          }
        }
        {
          // stage weights for (tap, icc): 4KB
          size_t w16 = ((size_t)(tap * 8 + icc) * 16 + mb * 4 + (t >> 6)) * 64 + (t & 63);
          gload_lds16(wpk + w16 * 8, &wlds[(size_t)t * 8]);
        }
        __syncthreads();

        const int dy = tap / 3, dx = tap - 3 * (tap / 3);
        bf16x8 af[4];
#pragma unroll
        for (int mi = 0; mi < 4; mi++)
          af[mi] = *(const bf16x8*)&wlds[(size_t)(mi * 64 + l) * 8];
#pragma unroll
        for (int nf = 0; nf < 4; nf++) {
          int pl = wv * 64 + nf * 16 + l15;
          int py = pl >> LW;
          int c = pl & (W - 1);
          int tcol = c + dx;
          int idx16 = ((py + dy) * Cw + tcol) * 4 + (l4 ^ (tcol & 3));
          bf16x8 bfv = *(const bf16x8*)&tin[(size_t)idx16 * 8];
#pragma unroll
          for (int mi = 0; mi < 4; mi++)
            acc[mi][nf] = __builtin_amdgcn_mfma_f32_16x16x32_bf16(af[mi], bfv, acc[mi][nf], 0, 0, 0);
        }
      }
    }
  }

  // epilogue
#pragma unroll
  for (int mi = 0; mi < 4; mi++) {
    int oc0 = mb * 64 + mi * 16 + l4 * 4;
    float bv[4];
#pragma unroll
    for (int rr = 0; rr < 4; rr++) bv[rr] = bias ? bias[oc0 + rr] : 0.f;
#pragma unroll
    for (int nf = 0; nf < 4; nf++) {
      int p = pixbase + wv * 64 + nf * 16 + l15;
      if (NCHWOUT) {
        float* o = (float*)outp;
        int pin = p & (HW - 1);
        int bb2 = p >> (2 * LW);
#pragma unroll
        for (int rr = 0; rr < 4; rr++)
          o[((size_t)(bb2 * CDIM + oc0 + rr)) * HW + pin] = lrelu(acc[mi][nf][rr] + bv[rr]);
      } else {
        unsigned short* o = (unsigned short*)outp;
        ushort4 pk;
        pk.x = f2bf(lrelu(acc[mi][nf][0] + bv[0]));
        pk.y = f2bf(lrelu(acc[mi][nf][1] + bv[1]));
        pk.z = f2bf(lrelu(acc[mi][nf][2] + bv[2]));
        pk.w = f2bf(lrelu(acc[mi][nf][3] + bv[3]));
        *(ushort4*)&o[(size_t)p * CDIM + oc0] = pk;
      }
    }
  }
}

// ---------------- host ----------------
extern "C" void kernel_launch(void* const* d_in, const int* in_sizes, int n_in,
                              void* d_out, int out_size, void* d_ws, size_t ws_size,
                              hipStream_t stream) {
  (void)in_sizes; (void)n_in; (void)out_size;
  const float* c_hf = (const float*)d_in[0];
  const float* c_lf = (const float*)d_in[1];
  const float* s_hf = (const float*)d_in[2];
  const float* s_lf = (const float*)d_in[3];
  const float* h_sw = (const float*)d_in[4];
  const float* h_sb = (const float*)d_in[5];
  const float* h_pw = (const float*)d_in[6];
  const float* h_pb = (const float*)d_in[7];
  const float* h_bw = (const float*)d_in[8];
  const float* h_bb = (const float*)d_in[9];
  const float* l_sw = (const float*)d_in[10];
  const float* l_sb = (const float*)d_in[11];
  const float* l_pw = (const float*)d_in[12];
  const float* l_pb = (const float*)d_in[13];
  const float* l_bw = (const float*)d_in[14];
  const float* l_bb = (const float*)d_in[15];
  const float* ada_h_w = (const float*)d_in[16];
  const float* ada_h_b = (const float*)d_in[17];
  const float* ada_l_w = (const float*)d_in[18];
  const float* ada_l_b = (const float*)d_in[19];
  const float* h2h = (const float*)d_in[20];
  const float* l2h = (const float*)d_in[21];
  const float* h2l = (const float*)d_in[22];
  const float* l2l = (const float*)d_in[23];

  const int B = 4, H = 128, W = 128;

  float* base;
  size_t need = (size_t)TOTAL_F * sizeof(float);
  if (ws_size >= need) {
    base = (float*)d_ws;
  } else {
    void* p = nullptr;
    hipGetSymbolAddress(&p, HIP_SYMBOL(g_scratch));
    base = (float*)p;
  }

  float* ws_hf = base + OFF_WS_HF;
  float* ws_lf = base + OFF_WS_LF;
  float* pool_hf = base + OFF_POOL_HF;
  float* pool_lf = base + OFF_POOL_LF;
  float* wp_hf = base + OFF_WP_HF;
  float* bs_hf = base + OFF_BS_HF;
  float* wp_lf = base + OFF_WP_LF;
  float* bs_lf = base + OFF_BS_LF;
  float* mean_hf = base + OFF_MEAN_HF;
  float* rstd_hf = base + OFF_RSTD_HF;
  float* mean_lf = base + OFF_MEAN_LF;
  float* rstd_lf = base + OFF_RSTD_LF;
  unsigned short* u16 = (unsigned short*)(base + OFF_U16);
  unsigned short* yh = u16 + U_YH;
  unsigned short* yl = u16 + U_YL;
  unsigned short* hfA = u16 + U_HFA;
  unsigned short* lfA = u16 + U_LFA;
  unsigned short* hfP = u16 + U_HFP;
  unsigned short* pk_adah = u16 + U_PK + 0 * PK_SZ;
  unsigned short* pk_h2h  = u16 + U_PK + 1 * PK_SZ;
  unsigned short* pk_l2h  = u16 + U_PK + 2 * PK_SZ;
  unsigned short* pk_adal = u16 + U_PK + 3 * PK_SZ;
  unsigned short* pk_l2l  = u16 + U_PK + 4 * PK_SZ;
  unsigned short* pk_h2l  = u16 + U_PK + 5 * PK_SZ;

  float* out_hf = (float*)d_out;
  float* out_lf = (float*)d_out + 16777216;

  // weight packing
  k_packw<<<dim3(2304), dim3(256), 0, stream>>>(ada_h_w, pk_adah);
  k_packw<<<dim3(2304), dim3(256), 0, stream>>>(h2h, pk_h2h);
  k_packw<<<dim3(2304), dim3(256), 0, stream>>>(l2h, pk_l2h);
  k_packw<<<dim3(2304), dim3(256), 0, stream>>>(ada_l_w, pk_adal);
  k_packw<<<dim3(2304), dim3(256), 0, stream>>>(l2l, pk_l2l);
  k_packw<<<dim3(2304), dim3(256), 0, stream>>>(h2l, pk_h2l);

  // kernel_predict
  k_ws<<<dim3(B * CDIM), dim3(256), 0, stream>>>(s_hf, h_sw, h_sb, ws_hf);
  k_ws<<<dim3(B * CDIM), dim3(256), 0, stream>>>(s_lf, l_sw, l_sb, ws_lf);
  k_pool<<<dim3(4), dim3(256), 0, stream>>>(s_hf, pool_hf, B * CDIM);
  k_pool<<<dim3(4), dim3(256), 0, stream>>>(s_lf, pool_lf, B * CDIM);
  k_point<<<dim3(B), dim3(256), 0, stream>>>(pool_hf, h_pw, h_pb, h_bw, h_bb, wp_hf, bs_hf);
  k_point<<<dim3(B), dim3(256), 0, stream>>>(pool_lf, l_pw, l_pb, l_bw, l_bb, wp_lf, bs_lf);

  // instance norm stats
  k_istats<<<dim3(B * CDIM), dim3(256), 0, stream>>>(c_hf, mean_hf, rstd_hf, H * W);
  k_istats<<<dim3(B * CDIM), dim3(256), 0, stream>>>(c_lf, mean_lf, rstd_lf, (H / 2) * (W / 2));

  // fused IN + depthwise + pointwise -> NHWC bf16
  k_dwt<7><<<dim3(8, 128, 4), dim3(256), 0, stream>>>(c_hf, ws_hf, mean_hf, rstd_hf, wp_hf, bs_hf, yh);
  k_dwt<6><<<dim3(4, 64, 4), dim3(256), 0, stream>>>(c_lf, ws_lf, mean_lf, rstd_lf, wp_lf, bs_lf, yl);

  // ada convs (MFMA), bf16 NHWC out, lrelu
  k_conv_mfma<7, false, false, false><<<dim3(256, 4), dim3(256), 0, stream>>>(
      yh, nullptr, pk_adah, nullptr, ada_h_b, hfA);
  k_conv_mfma<6, false, false, false><<<dim3(64, 4), dim3(256), 0, stream>>>(
      yl, nullptr, pk_adal, nullptr, ada_l_b, lfA);

  // avgpool hf
  k_pool_nhwc<<<dim3(16384), dim3(256), 0, stream>>>(hfA, hfP);

  // fused output convs (MFMA), f32 NCHW out, lrelu
  k_conv_mfma<7, true, true, true><<<dim3(256, 4), dim3(256), 0, stream>>>(
      hfA, lfA, pk_h2h, pk_l2h, nullptr, out_hf);
  k_conv_mfma<6, true, false, true><<<dim3(64, 4), dim3(256), 0, stream>>>(
      lfA, hfP, pk_l2l, pk_h2l, nullptr, out_lf);
}

// Round 3
// 514.195 us; speedup vs baseline: 14.3719x; 1.2415x over previous
//
#include <hip/hip_runtime.h>
#include <hip/hip_bf16.h>

#define CDIM 256
#define EPS 1e-5f
#define SLOPE 0.01f

using f32x4  = __attribute__((ext_vector_type(4))) float;
typedef __bf16 bf16x8 __attribute__((ext_vector_type(8)));

// ---------------- workspace layout ----------------
enum : size_t {
  OFF_WS_HF   = 0,
  OFF_WS_LF   = 9216,
  OFF_POOL_HF = 18432,
  OFF_POOL_LF = 19456,
  OFF_WP_HF   = 20480,
  OFF_BS_HF   = 21504,
  OFF_WP_LF   = 22528,
  OFF_BS_LF   = 23552,
  OFF_MEAN_HF = 24576,
  OFF_RSTD_HF = 25600,
  OFF_MEAN_LF = 26624,
  OFF_RSTD_LF = 27648,
  OFF_U16     = 32768,          // start of ushort region (float units)
};
// ushort offsets relative to u16 base
enum : size_t {
  U_YH  = 0,          // [4][128][128][256] bf16
  U_YL  = 16777216,   // [4][64][64][256]
  U_HFA = 20971520,   // [4][128][128][256]
  U_LFA = 37748736,   // [4][64][64][256]
  U_HFP = 41943040,   // [4][64][64][256]
  U_PK  = 46137344,   // 6 packed weights, each 589824
  PK_SZ = 589824,
  U_END = U_PK + 6 * PK_SZ,
};
enum : size_t { TOTAL_F = OFF_U16 + (U_END + 1) / 2 };

__device__ float g_scratch[TOTAL_F];

__device__ __forceinline__ int refl(int q, int n) {
  return q < 0 ? -q : (q >= n ? 2 * n - 2 - q : q);
}
__device__ __forceinline__ float lrelu(float v) { return v >= 0.f ? v : SLOPE * v; }
__device__ __forceinline__ unsigned short f2bf(float f) {
  unsigned int u = __float_as_uint(f);
  u += 0x7fffu + ((u >> 16) & 1u);
  return (unsigned short)(u >> 16);
}
__device__ __forceinline__ float bf2f(unsigned short h) {
  return __uint_as_float(((unsigned int)h) << 16);
}
__device__ __forceinline__ void gload_lds16(const void* g, void* l) {
  __builtin_amdgcn_global_load_lds(
      (const __attribute__((address_space(1))) unsigned int*)g,
      (__attribute__((address_space(3))) unsigned int*)l, 16, 0, 0);
}

// ---------------- kernel_predict: spatial weights ----------------
__global__ __launch_bounds__(256) void k_ws(const float* __restrict__ s,
                                            const float* __restrict__ sw,
                                            const float* __restrict__ sb,
                                            float* __restrict__ ws_out) {
  int bo = blockIdx.x;
  int o = bo & (CDIM - 1);
  int c = threadIdx.x;
  int b = bo >> 8;
  float sv[9], wv[9];
  const float* sp = s + (size_t)(b * CDIM + c) * 9;
  const float* wp = sw + (size_t)(o * CDIM + c) * 9;
#pragma unroll
  for (int i = 0; i < 9; i++) { sv[i] = sp[i]; wv[i] = wp[i]; }
  float out9[9];
#pragma unroll
  for (int i = 0; i < 3; i++)
#pragma unroll
    for (int j = 0; j < 3; j++) {
      float a = 0.f;
#pragma unroll
      for (int dy = 0; dy < 3; dy++) {
        int u = i + dy - 1; u = (u < 0) ? 1 : (u > 2 ? 1 : u);
#pragma unroll
        for (int dx = 0; dx < 3; dx++) {
          int v = j + dx - 1; v = (v < 0) ? 1 : (v > 2 ? 1 : v);
          a += sv[u * 3 + v] * wv[dy * 3 + dx];
        }
      }
      out9[i * 3 + j] = a;
    }
  __shared__ float red[256 * 9];
#pragma unroll
  for (int i = 0; i < 9; i++) red[c * 9 + i] = out9[i];
  __syncthreads();
  for (int st = 128; st > 0; st >>= 1) {
    if (c < st)
#pragma unroll
      for (int i = 0; i < 9; i++) red[c * 9 + i] += red[(c + st) * 9 + i];
    __syncthreads();
  }
  if (c < 9) ws_out[(size_t)bo * 9 + c] = red[c] + sb[o];
}

__global__ void k_pool(const float* __restrict__ s, float* __restrict__ pooled, int n) {
  int i = blockIdx.x * 256 + threadIdx.x;
  if (i >= n) return;
  const float* p = s + (size_t)i * 9;
  float a = 0.f;
#pragma unroll
  for (int j = 0; j < 9; j++) a += p[j];
  pooled[i] = a * (1.f / 9.f);
}

__global__ __launch_bounds__(256) void k_point(const float* __restrict__ pooled,
                                               const float* __restrict__ pw,
                                               const float* __restrict__ pb,
                                               const float* __restrict__ bw,
                                               const float* __restrict__ bb,
                                               float* __restrict__ wp_out,
                                               float* __restrict__ bs_out) {
  int b = blockIdx.x, o = threadIdx.x;
  __shared__ float pl[CDIM];
  pl[o] = pooled[b * CDIM + o];
  __syncthreads();
  float a = pb[o], d = bb[o];
  for (int c = 0; c < CDIM; c++) {
    float p = pl[c];
    a += p * pw[o * CDIM + c];
    d += p * bw[o * CDIM + c];
  }
  wp_out[b * CDIM + o] = a;
  bs_out[b * CDIM + o] = d;
}

__global__ __launch_bounds__(256) void k_istats(const float* __restrict__ x,
                                                float* __restrict__ mean,
                                                float* __restrict__ rstd, int HW) {
  int plane = blockIdx.x;
  const float4* p = (const float4*)(x + (size_t)plane * HW);
  int n4 = HW >> 2;
  float s = 0.f, q = 0.f;
  for (int i = threadIdx.x; i < n4; i += 256) {
    float4 v = p[i];
    s += v.x + v.y + v.z + v.w;
    q += v.x * v.x + v.y * v.y + v.z * v.z + v.w * v.w;
  }
  __shared__ float rs[256], rq[256];
  rs[threadIdx.x] = s; rq[threadIdx.x] = q;
  __syncthreads();
  for (int st = 128; st > 0; st >>= 1) {
    if (threadIdx.x < st) {
      rs[threadIdx.x] += rs[threadIdx.x + st];
      rq[threadIdx.x] += rq[threadIdx.x + st];
    }
    __syncthreads();
  }
  if (threadIdx.x == 0) {
    float m = rs[0] / HW;
    float v = rq[0] / HW - m * m;
    mean[plane] = m;
    rstd[plane] = rsqrtf(v + EPS);
  }
}

// ---------------- weight pack: OIHW f32 -> [tap][icc][mf][lane][8] bf16 (6 mats) ----------------
__global__ void k_packw6(const float* __restrict__ w0, const float* __restrict__ w1,
                         const float* __restrict__ w2, const float* __restrict__ w3,
                         const float* __restrict__ w4, const float* __restrict__ w5,
                         unsigned short* __restrict__ pk) {
  const float* ws[6] = {w0, w1, w2, w3, w4, w5};
  int seg = blockIdx.y;
  const float* w = ws[seg];
  int i = blockIdx.x * 256 + threadIdx.x;   // < 589824
  int j = i & 7, l = (i >> 3) & 63, mf = (i >> 9) & 15, icc = (i >> 13) & 7, tap = i >> 16;
  int oc = mf * 16 + (l & 15);
  int ic = icc * 32 + (l >> 4) * 8 + j;
  pk[(size_t)seg * PK_SZ + i] = f2bf(w[((size_t)oc * 256 + ic) * 9 + tap]);
}

// ---------------- fused IN + dynamic depthwise + pointwise -> NHWC bf16 ----------------
template <int LW>
__global__ __launch_bounds__(256) void k_dwt(const float* __restrict__ x,
                                             const float* __restrict__ ws,
                                             const float* __restrict__ mean,
                                             const float* __restrict__ rstd,
                                             const float* __restrict__ wp,
                                             const float* __restrict__ bs,
                                             unsigned short* __restrict__ out) {
  constexpr int W = 1 << LW, H = W, HW = W * W;
  int t = threadIdx.x;
  int xt = (LW > 6) ? (blockIdx.x & ((W >> 6) - 1)) : 0;
  int icb = (LW > 6) ? (blockIdx.x >> (LW - 6)) : blockIdx.x;
  int y = blockIdx.y, b = blockIdx.z;
  __shared__ unsigned short tr[64][66];
  int xl = t & 63;
  int xx = xt * 64 + xl;
  int sy0 = refl(y - 1, H), sy1 = y, sy2 = refl(y + 1, H);
  int sx0 = refl(xx - 1, W), sx2 = refl(xx + 1, W);
#pragma unroll
  for (int rr = 0; rr < 16; ++rr) {
    int icl = rr * 4 + (t >> 6);
    int plane = b * CDIM + icb * 64 + icl;
    const float* xp = x + (size_t)plane * HW;
    float m = mean[plane], r = rstd[plane], sc = wp[plane], bi = bs[plane];
    const float* w9 = ws + (size_t)plane * 9;
    float a = w9[0] * (xp[sy0 * W + sx0] - m) + w9[1] * (xp[sy0 * W + xx] - m) +
              w9[2] * (xp[sy0 * W + sx2] - m) + w9[3] * (xp[sy1 * W + sx0] - m) +
              w9[4] * (xp[sy1 * W + xx] - m) + w9[5] * (xp[sy1 * W + sx2] - m) +
              w9[6] * (xp[sy2 * W + sx0] - m) + w9[7] * (xp[sy2 * W + xx] - m) +
              w9[8] * (xp[sy2 * W + sx2] - m);
    tr[icl][xl] = f2bf(a * r * sc + bi);
  }
  __syncthreads();
#pragma unroll
  for (int rr = 0; rr < 16; ++rr) {
    int xl2 = rr * 4 + (t >> 6);
    int icl2 = t & 63;
    out[((size_t)((b * H + y) * W + xt * 64 + xl2)) * CDIM + icb * 64 + icl2] = tr[icl2][xl2];
  }
}

// ---------------- 2x2 avg pool on NHWC bf16 ----------------
__global__ __launch_bounds__(256) void k_pool_nhwc(const unsigned short* __restrict__ in,
                                                   unsigned short* __restrict__ out) {
  int t = threadIdx.x;
  int p = blockIdx.x;                 // (b*64+Y)*64+X
  int X = p & 63, Y = (p >> 6) & 63, b = p >> 12;
  const unsigned short* s = in + (((size_t)(b * 128 + 2 * Y) * 128 + 2 * X) * CDIM + t);
  float a = bf2f(s[0]) + bf2f(s[CDIM]) + bf2f(s[128 * CDIM]) + bf2f(s[128 * CDIM + CDIM]);
  out[(size_t)p * CDIM + t] = f2bf(0.25f * a);
}

// ---------------- MFMA implicit-GEMM 3x3 reflect conv ----------------
// block 256 (4 waves), tile 64 oc x 256 pixels. Per icc-step: stage input 32ic
// tile + ALL 9 taps' weights once, then 144 MFMA between 2 barriers.
// grid(4 ocgroups [x, fastest for L2 temporal locality], npix/256 [y]).
template <int LW, bool DUAL, bool UPSB, bool NCHWOUT>
__global__ __launch_bounds__(256, 2) void k_conv_mfma(
    const unsigned short* __restrict__ srcA, const unsigned short* __restrict__ srcB,
    const unsigned short* __restrict__ wpkA, const unsigned short* __restrict__ wpkB,
    const float* __restrict__ bias, void* __restrict__ outp) {
  constexpr int W = 1 << LW, H = W, HW = W * W;
  constexpr int ROWS = 256 >> LW;       // pixel rows per block
  constexpr int R = ROWS + 2, Cw = W + 2;
  constexpr int RC = R * Cw;
  constexpr int RCPAD = (RC + 63) & ~63;
  constexpr int NIT = RCPAD / 64;
  __shared__ __align__(16) unsigned short tin[RCPAD * 32];        // input tile, 32 ic
  __shared__ __align__(16) unsigned short wlds[9 * 4 * 64 * 8];   // 9 taps x 4 mi frags

  const int t = threadIdx.x;
  const int l = t & 63, wv = t >> 6;
  const int l15 = l & 15, l4 = l >> 4;
  const int mb = blockIdx.x;
  const int pixbase = blockIdx.y * 256;
  const int b = pixbase >> (2 * LW);
  const int y0 = (pixbase >> LW) & (H - 1);

  f32x4 acc[4][4];
#pragma unroll
  for (int mi = 0; mi < 4; mi++)
#pragma unroll
    for (int nf = 0; nf < 4; nf++) acc[mi][nf] = (f32x4){0.f, 0.f, 0.f, 0.f};

  const int nsrc = DUAL ? 2 : 1;
  for (int src = 0; src < nsrc; ++src) {
    const unsigned short* ysrc = src ? srcB : srcA;
    const unsigned short* wpk = src ? wpkB : wpkA;
    const bool ups = UPSB && (src == 1);

    // hoist staging addresses out of the K loop
    const unsigned short* inptr[NIT];
#pragma unroll
    for (int it = 0; it < NIT; ++it) {
      int rc = it * 64 + (t >> 2);
      int rcc = rc < RC - 1 ? rc : RC - 1;
      int r = rcc / Cw, tc = rcc - r * Cw;
      int gy = refl(y0 - 1 + r, H);
      int gx = refl(tc - 1, W);
      int sy, sx, sw;
      if (ups) { sy = gy >> 1; sx = gx >> 1; sw = W >> 1; }
      else     { sy = gy;      sx = gx;      sw = W; }
      int gsrc = (t & 3) ^ (tc & 3);   // ic-slot XOR swizzle (source side)
      inptr[it] = ysrc + (((size_t)(b * sw + sy) * sw + sx) * CDIM + gsrc * 8);
    }
    const unsigned short* wsrc = wpk + ((size_t)(mb * 4 + (t >> 6)) * 64 + (t & 63)) * 8;

    for (int icc = 0; icc < 8; ++icc) {
      __syncthreads();
#pragma unroll
      for (int it = 0; it < NIT; ++it)
        gload_lds16(inptr[it] + icc * 32, &tin[(size_t)(it * 256 + t) * 8]);
#pragma unroll
      for (int tap = 0; tap < 9; ++tap)
        gload_lds16(wsrc + ((size_t)tap * 8 + (size_t)icc) * 8192,
                    &wlds[(size_t)(tap * 256 + t) * 8]);
      __syncthreads();

#pragma unroll
      for (int tap = 0; tap < 9; ++tap) {
        const int dy = tap / 3, dx = tap - 3 * (tap / 3);
        bf16x8 af[4];
#pragma unroll
        for (int mi = 0; mi < 4; mi++)
          af[mi] = *(const bf16x8*)&wlds[(size_t)((tap * 4 + mi) * 64 + l) * 8];
#pragma unroll
        for (int nf = 0; nf < 4; nf++) {
          int pl = wv * 64 + nf * 16 + l15;
          int py = pl >> LW;
          int c = pl & (W - 1);
          int tcol = c + dx;
          int idx16 = ((py + dy) * Cw + tcol) * 4 + (l4 ^ (tcol & 3));
          bf16x8 bfv = *(const bf16x8*)&tin[(size_t)idx16 * 8];
#pragma unroll
          for (int mi = 0; mi < 4; mi++)
            acc[mi][nf] = __builtin_amdgcn_mfma_f32_16x16x32_bf16(af[mi], bfv, acc[mi][nf], 0, 0, 0);
        }
      }
    }
  }

  // epilogue
#pragma unroll
  for (int mi = 0; mi < 4; mi++) {
    int oc0 = mb * 64 + mi * 16 + l4 * 4;
    float bv[4];
#pragma unroll
    for (int rr = 0; rr < 4; rr++) bv[rr] = bias ? bias[oc0 + rr] : 0.f;
#pragma unroll
    for (int nf = 0; nf < 4; nf++) {
      int p = pixbase + wv * 64 + nf * 16 + l15;
      if (NCHWOUT) {
        float* o = (float*)outp;
        int pin = p & (HW - 1);
        int bb2 = p >> (2 * LW);
#pragma unroll
        for (int rr = 0; rr < 4; rr++)
          o[((size_t)(bb2 * CDIM + oc0 + rr)) * HW + pin] = lrelu(acc[mi][nf][rr] + bv[rr]);
      } else {
        unsigned short* o = (unsigned short*)outp;
        ushort4 pk;
        pk.x = f2bf(lrelu(acc[mi][nf][0] + bv[0]));
        pk.y = f2bf(lrelu(acc[mi][nf][1] + bv[1]));
        pk.z = f2bf(lrelu(acc[mi][nf][2] + bv[2]));
        pk.w = f2bf(lrelu(acc[mi][nf][3] + bv[3]));
        *(ushort4*)&o[(size_t)p * CDIM + oc0] = pk;
      }
    }
  }
}

// ---------------- host ----------------
extern "C" void kernel_launch(void* const* d_in, const int* in_sizes, int n_in,
                              void* d_out, int out_size, void* d_ws, size_t ws_size,
                              hipStream_t stream) {
  (void)in_sizes; (void)n_in; (void)out_size;
  const float* c_hf = (const float*)d_in[0];
  const float* c_lf = (const float*)d_in[1];
  const float* s_hf = (const float*)d_in[2];
  const float* s_lf = (const float*)d_in[3];
  const float* h_sw = (const float*)d_in[4];
  const float* h_sb = (const float*)d_in[5];
  const float* h_pw = (const float*)d_in[6];
  const float* h_pb = (const float*)d_in[7];
  const float* h_bw = (const float*)d_in[8];
  const float* h_bb = (const float*)d_in[9];
  const float* l_sw = (const float*)d_in[10];
  const float* l_sb = (const float*)d_in[11];
  const float* l_pw = (const float*)d_in[12];
  const float* l_pb = (const float*)d_in[13];
  const float* l_bw = (const float*)d_in[14];
  const float* l_bb = (const float*)d_in[15];
  const float* ada_h_w = (const float*)d_in[16];
  const float* ada_h_b = (const float*)d_in[17];
  const float* ada_l_w = (const float*)d_in[18];
  const float* ada_l_b = (const float*)d_in[19];
  const float* h2h = (const float*)d_in[20];
  const float* l2h = (const float*)d_in[21];
  const float* h2l = (const float*)d_in[22];
  const float* l2l = (const float*)d_in[23];

  const int B = 4, H = 128, W = 128;

  float* base;
  size_t need = (size_t)TOTAL_F * sizeof(float);
  if (ws_size >= need) {
    base = (float*)d_ws;
  } else {
    void* p = nullptr;
    hipGetSymbolAddress(&p, HIP_SYMBOL(g_scratch));
    base = (float*)p;
  }

  float* ws_hf = base + OFF_WS_HF;
  float* ws_lf = base + OFF_WS_LF;
  float* pool_hf = base + OFF_POOL_HF;
  float* pool_lf = base + OFF_POOL_LF;
  float* wp_hf = base + OFF_WP_HF;
  float* bs_hf = base + OFF_BS_HF;
  float* wp_lf = base + OFF_WP_LF;
  float* bs_lf = base + OFF_BS_LF;
  float* mean_hf = base + OFF_MEAN_HF;
  float* rstd_hf = base + OFF_RSTD_HF;
  float* mean_lf = base + OFF_MEAN_LF;
  float* rstd_lf = base + OFF_RSTD_LF;
  unsigned short* u16 = (unsigned short*)(base + OFF_U16);
  unsigned short* yh = u16 + U_YH;
  unsigned short* yl = u16 + U_YL;
  unsigned short* hfA = u16 + U_HFA;
  unsigned short* lfA = u16 + U_LFA;
  unsigned short* hfP = u16 + U_HFP;
  unsigned short* pk      = u16 + U_PK;
  unsigned short* pk_adah = pk + 0 * PK_SZ;
  unsigned short* pk_h2h  = pk + 1 * PK_SZ;
  unsigned short* pk_l2h  = pk + 2 * PK_SZ;
  unsigned short* pk_adal = pk + 3 * PK_SZ;
  unsigned short* pk_l2l  = pk + 4 * PK_SZ;
  unsigned short* pk_h2l  = pk + 5 * PK_SZ;

  float* out_hf = (float*)d_out;
  float* out_lf = (float*)d_out + 16777216;

  // weight packing (6 matrices in one launch)
  k_packw6<<<dim3(2304, 6), dim3(256), 0, stream>>>(ada_h_w, h2h, l2h, ada_l_w, l2l, h2l, pk);

  // kernel_predict
  k_ws<<<dim3(B * CDIM), dim3(256), 0, stream>>>(s_hf, h_sw, h_sb, ws_hf);
  k_ws<<<dim3(B * CDIM), dim3(256), 0, stream>>>(s_lf, l_sw, l_sb, ws_lf);
  k_pool<<<dim3(4), dim3(256), 0, stream>>>(s_hf, pool_hf, B * CDIM);
  k_pool<<<dim3(4), dim3(256), 0, stream>>>(s_lf, pool_lf, B * CDIM);
  k_point<<<dim3(B), dim3(256), 0, stream>>>(pool_hf, h_pw, h_pb, h_bw, h_bb, wp_hf, bs_hf);
  k_point<<<dim3(B), dim3(256), 0, stream>>>(pool_lf, l_pw, l_pb, l_bw, l_bb, wp_lf, bs_lf);

  // instance norm stats
  k_istats<<<dim3(B * CDIM), dim3(256), 0, stream>>>(c_hf, mean_hf, rstd_hf, H * W);
  k_istats<<<dim3(B * CDIM), dim3(256), 0, stream>>>(c_lf, mean_lf, rstd_lf, (H / 2) * (W / 2));

  // fused IN + depthwise + pointwise -> NHWC bf16
  k_dwt<7><<<dim3(8, 128, 4), dim3(256), 0, stream>>>(c_hf, ws_hf, mean_hf, rstd_hf, wp_hf, bs_hf, yh);
  k_dwt<6><<<dim3(4, 64, 4), dim3(256), 0, stream>>>(c_lf, ws_lf, mean_lf, rstd_lf, wp_lf, bs_lf, yl);

  // ada convs (MFMA), bf16 NHWC out, lrelu
  k_conv_mfma<7, false, false, false><<<dim3(4, 256), dim3(256), 0, stream>>>(
      yh, nullptr, pk_adah, nullptr, ada_h_b, hfA);
  k_conv_mfma<6, false, false, false><<<dim3(4, 64), dim3(256), 0, stream>>>(
      yl, nullptr, pk_adal, nullptr, ada_l_b, lfA);

  // avgpool hf
  k_pool_nhwc<<<dim3(16384), dim3(256), 0, stream>>>(hfA, hfP);

  // fused output convs (MFMA), f32 NCHW out, lrelu
  k_conv_mfma<7, true, true, true><<<dim3(4, 256), dim3(256), 0, stream>>>(
      hfA, lfA, pk_h2h, pk_l2h, nullptr, out_hf);
  k_conv_mfma<6, true, false, true><<<dim3(4, 64), dim3(256), 0, stream>>>(
      lfA, hfP, pk_l2l, pk_h2l, nullptr, out_lf);
}